// Round 2
// baseline (481.864 us; speedup 1.0000x reference)
//
#include <hip/hip_runtime.h>
#include <math.h>

#define HH 721
#define WW 1440
#define HWV (HH*WW)        // 1038240
#define NB 16
#define NC 4
#define ND 256
#define NL 4
#define NQ (HWV/4)         // 259560 float4 quads per plane

#define PHI_F 1.61803398874989484820458683436564f

typedef float vfloat4 __attribute__((ext_vector_type(4)));

__constant__ float c_rx[12] = {-1.f, 1.f, -1.f, 1.f,  0.f, 0.f, 0.f, 0.f,
                               PHI_F, PHI_F, -PHI_F, -PHI_F};
__constant__ float c_ry[12] = {PHI_F, PHI_F, -PHI_F, -PHI_F, -1.f, 1.f, -1.f, 1.f,
                               0.f, 0.f, 0.f, 0.f};
__constant__ float c_rz[12] = {0.f, 0.f, 0.f, 0.f, PHI_F, PHI_F, -PHI_F, -PHI_F,
                               -1.f, 1.f, -1.f, 1.f};
// icosahedron adjacency (deg = 5 for every vertex)
__constant__ int c_nbr[12][5] = {
    {11, 5, 1, 7, 10}, {0, 5, 7, 9, 8}, {11, 10, 3, 4, 6}, {9, 4, 2, 6, 8},
    {5, 11, 3, 9, 2},  {0, 11, 1, 9, 4}, {10, 7, 3, 2, 8}, {0, 1, 10, 6, 8},
    {7, 1, 3, 6, 9},   {1, 5, 3, 4, 8},  {0, 7, 11, 2, 6}, {0, 5, 10, 4, 2}};

__device__ __forceinline__ void vert_latlon(int v, double* olat, double* olon) {
#pragma clang fp contract(off)
  const float P = PHI_F;
  float n = sqrtf(1.0f + P * P);
  float xf = c_rx[v] / n;
  float yf = c_ry[v] / n;
  float zf = c_rz[v] / n;
  *olat = asin((double)zf);
  *olon = atan2((double)yf, (double)xf);
}

__device__ __forceinline__ double grid_lat(int i) {
#pragma clang fp contract(off)
  if (i == 720) return M_PI / 2;
  double v = (double)i * (M_PI / 720.0);
  return v - M_PI / 2;
}

__device__ __forceinline__ double grid_lon(int j) {
#pragma clang fp contract(off)
  if (j == 1439) return M_PI;
  double v = (double)j * (2.0 * M_PI / 1439.0);
  return v - M_PI;
}

__device__ __forceinline__ double d2f(double lat, double lon, double vlat,
                                      double vlon) {
#pragma clang fp contract(off)
  double dlat = lat - vlat;
  double x = (lon - vlon) + M_PI;
  const double TP = 2.0 * M_PI;
  double r = (x < 0.0) ? (x + TP) : ((x >= TP) ? (x - TP) : x);
  double dlon = r - M_PI;
  return dlat * dlat + dlon * dlon;
}

// --- kernel 1: v2g window-argmin + tiny GNN, one block per batch -----------
// 1024 threads (16 waves -> 4 waves/SIMD for latency hiding).
// Thread (g = t>>8, d = t&255) owns nodes n in {3g..3g+2} at dim d.
// hn state lives in LDS s_hn[12][256]; A-operand broadcasts read as
// ds_read_b128 (wave-uniform addr) -> 4x fewer LDS instructions.
// Accumulation order per output is bit-identical to the verified 524.6 µs
// kernel (same dd-increasing fmac chain, same neighbor order, same /5.0f).
__global__ __launch_bounds__(1024) void gnn_kernel(
    const float* __restrict__ x, const float* __restrict__ W_in,
    const float* __restrict__ b_in, const float* __restrict__ W_layers,
    const float* __restrict__ b_layers, const float* __restrict__ W_out,
    const float* __restrict__ b_out, float* __restrict__ out_tbl) {
  __shared__ int s_v2g[12];
  __shared__ float s_feats[12][4];
  __shared__ float s_hn[12][ND];
  __shared__ float s_agg[12][ND];
  const int b = blockIdx.x;
  const int t = threadIdx.x;
  const int g = t >> 8;        // node group 0..3
  const int d = t & (ND - 1);  // feature dim 0..255
  const int n0 = g * 3;

  if (t < 12) {
    double vlat, vlon;
    vert_latlon(t, &vlat, &vlon);
    int i0 = (int)floor((vlat + M_PI / 2) / (M_PI / 720.0) + 0.5);
    int j0 = (int)floor((vlon + M_PI) / (2.0 * M_PI / 1439.0) + 0.5);
    int cand[11] = {0, 1, 2, 1437, 1438, 1439, j0 - 2, j0 - 1, j0, j0 + 1, j0 + 2};
    for (int a = 6; a < 11; a++) {
      if (cand[a] < 0) cand[a] = 0;
      if (cand[a] > 1439) cand[a] = 1439;
    }
    for (int a = 1; a < 11; a++) {
      int key = cand[a];
      int p = a - 1;
      while (p >= 0 && cand[p] > key) {
        cand[p + 1] = cand[p];
        p--;
      }
      cand[p + 1] = key;
    }
    double best = 1e300;
    int bi = 0;
    for (int ii = i0 - 2; ii <= i0 + 2; ii++) {
      if (ii < 0 || ii > 720) continue;
      double lat = grid_lat(ii);
      int prev = -1;
      for (int a = 0; a < 11; a++) {
        int j = cand[a];
        if (j == prev) continue;
        prev = j;
        double dq = d2f(lat, grid_lon(j), vlat, vlon);
        if (dq < best) {  // strict < == first-occurrence; R5 evidence says
          best = dq;      // the computed v2g is correct — no overrides.
          bi = ii * 1440 + j;
        }
      }
    }
    s_v2g[t] = bi;
  }
  __syncthreads();

  if (t < 48) {
    int n = t >> 2, c = t & 3;
    int k = s_v2g[n];
    s_feats[n][c] = x[(size_t)(b * NC + c) * HWV + k];
  }
  __syncthreads();

  // hn init: thread (g,d) computes its 3 nodes at dim d.
#pragma unroll
  for (int nn = 0; nn < 3; nn++) {
    int n = n0 + nn;
    float s = b_in[d];
#pragma unroll
    for (int c = 0; c < 4; c++) s += s_feats[n][c] * W_in[c * ND + d];
    s_hn[n][d] = s;
  }
  __syncthreads();

  for (int l = 0; l < NL; l++) {
    // agg stage: same neighbor order + /5.0f as before (bit-identical).
#pragma unroll
    for (int nn = 0; nn < 3; nn++) {
      int n = n0 + nn;
      float s = 0.f;
#pragma unroll
      for (int e = 0; e < 5; e++) s += s_hn[c_nbr[n][e]][d];
      s_agg[n][d] = s / 5.0f;
    }
    __syncthreads();

    // GEMM slice: acc[nn] = sum_dd s_agg[n][dd] * W[dd][d], dd increasing
    // (identical fmac chain order to the verified kernel).
    // unroll 8 groups -> >=8 W-loads in flight to cover L2 latency.
    float acc0 = 0.f, acc1 = 0.f, acc2 = 0.f;
    const float* Wl = W_layers + (size_t)l * ND * ND + d;
#pragma unroll 8
    for (int dd = 0; dd < ND; dd += 4) {
      vfloat4 a0 = *(const vfloat4*)&s_agg[n0 + 0][dd];  // broadcast b128
      vfloat4 a1 = *(const vfloat4*)&s_agg[n0 + 1][dd];
      vfloat4 a2 = *(const vfloat4*)&s_agg[n0 + 2][dd];
      float w0 = Wl[(size_t)(dd + 0) * ND];
      float w1 = Wl[(size_t)(dd + 1) * ND];
      float w2 = Wl[(size_t)(dd + 2) * ND];
      float w3 = Wl[(size_t)(dd + 3) * ND];
      acc0 += a0.x * w0; acc0 += a0.y * w1; acc0 += a0.z * w2; acc0 += a0.w * w3;
      acc1 += a1.x * w0; acc1 += a1.y * w1; acc1 += a1.z * w2; acc1 += a1.w * w3;
      acc2 += a2.x * w0; acc2 += a2.y * w1; acc2 += a2.z * w2; acc2 += a2.w * w3;
    }
    float bb = b_layers[l * ND + d];
    {
      float u0 = acc0 + bb;
      float u1 = acc1 + bb;
      float u2 = acc2 + bb;
      s_hn[n0 + 0][d] += (u0 > 0.f) ? u0 : 0.f;
      s_hn[n0 + 1][d] += (u1 > 0.f) ? u1 : 0.f;
      s_hn[n0 + 2][d] += (u2 > 0.f) ? u2 : 0.f;
    }
    __syncthreads();
  }

  // epilogue: identical serial loop to the verified kernel (reads s_hn,
  // which holds exactly the values the old kernel's s_agg held). Modeled
  // cost <=1 µs — kept serial to avoid reassociation risk.
  if (t < 48) {
    int n = t >> 2, c = t & 3;
    float s = b_out[c];
    for (int dd = 0; dd < ND; dd++) s += s_hn[n][dd] * W_out[dd * 4 + c];
    out_tbl[b * 48 + c * 12 + n] = s;
  }
}

// --- kernel 2: fused nearest-vertex mapping + scatter-write ----------------
// UNCHANGED (byte-identical to the verified kernel): carries harness-verified
// tie-break semantics (row-360 twin flip, first-occurrence strict <).
__global__ __launch_bounds__(256) void scatter_kernel(
    const float* __restrict__ tbl_g, float* __restrict__ out) {
  __shared__ float s_tbl[NB * NC * 12];
  __shared__ double svlat[12], svlon[12];
  const int t = threadIdx.x;
  if (t < 12) {
    double a, o;
    vert_latlon(t, &a, &o);
    svlat[t] = a;
    svlon[t] = o;
  }
  for (int i = t; i < NB * NC * 12; i += 256) s_tbl[i] = tbl_g[i];
  __syncthreads();

  int q = blockIdx.x * 256 + t;
  if (q >= NQ) return;
  int h = q / 360;
  int w4 = (q - h * 360) * 4;

  int v[4];
#pragma unroll
  for (int s2 = 0; s2 < 4; s2++) {
    int kk = (w4 + s2) * 721 + h;  // reference's reshape(lon,lat).T scramble
    int i2 = kk / 1440;
    int j2 = kk - i2 * 1440;
    double lat = grid_lat(i2);
    double lon = grid_lon(j2);
    double best = 1e300;
    int bv = 0;
#pragma unroll
    for (int vv = 0; vv < 12; vv++) {
      double dd = d2f(lat, lon, svlat[vv], svlon[vv]);
      if (dd < best) {
        best = dd;
        bv = vv;
      }
    }
    // --- R6 EXPERIMENT: equator row 360 sits at lat = (pi/2)(eps1+eps2),
    // a sub-ulp crumb. Vertex twins straddle the equator exactly
    // (asin is odd: vlat8 == -vlat9, vlat10 == -vlat11), so the whole
    // row-360 strip's winner is a coin decided by the crumb's sign.
    // Hypothesis: the reference's (XLA f32-native linspace) crumb has the
    // opposite sign to my f64/f32 chains -> flip the twin on row 360.
    if (i2 == 360 && bv >= 8) bv ^= 1;  // 8<->9, 10<->11
    v[s2] = bv;
  }

  vfloat4* out4 = (vfloat4*)out;
#pragma unroll
  for (int b = 0; b < NB; b++) {
#pragma unroll
    for (int c = 0; c < NC; c++) {
      const float* tb = &s_tbl[b * 48 + c * 12];
      vfloat4 val = {tb[v[0]], tb[v[1]], tb[v[2]], tb[v[3]]};
      __builtin_nontemporal_store(val, &out4[(size_t)(b * 4 + c) * NQ + q]);
    }
  }
}

extern "C" void kernel_launch(void* const* d_in, const int* in_sizes, int n_in,
                              void* d_out, int out_size, void* d_ws,
                              size_t ws_size, hipStream_t stream) {
  const float* x = (const float*)d_in[0];
  const float* W_in = (const float*)d_in[2];
  const float* b_in = (const float*)d_in[3];
  const float* W_layers = (const float*)d_in[4];
  const float* b_layers = (const float*)d_in[5];
  const float* W_out = (const float*)d_in[6];
  const float* b_out = (const float*)d_in[7];
  float* out = (float*)d_out;
  float* tbl = (float*)d_ws;

  gnn_kernel<<<NB, 1024, 0, stream>>>(x, W_in, b_in, W_layers, b_layers, W_out,
                                      b_out, tbl);
  int blocks = (NQ + 255) / 256;  // 1014
  scatter_kernel<<<blocks, 256, 0, stream>>>(tbl, out);
}

// Round 3
// 442.942 us; speedup vs baseline: 1.0879x; 1.0879x over previous
//
#include <hip/hip_runtime.h>
#include <math.h>

#define HH 721
#define WW 1440
#define HWV (HH*WW)        // 1038240
#define NB 16
#define NC 4
#define ND 256
#define NL 4
#define NQ (HWV/4)         // 259560 float4 quads per plane

#define PHI_F 1.61803398874989484820458683436564f

// ---- workspace layout (bytes) ----
#define WS_V2G 0                       // int[12]
#define WS_VLL 64                      // double[24]: vlat[12], vlon[12]
#define WS_TBL 512                     // float[16*48]
#define WS_HNA 4096                    // float[16*12*256]
#define WS_HNB (4096 + NB*12*ND*4)     // float[16*12*256]

typedef float vfloat4 __attribute__((ext_vector_type(4)));

__constant__ float c_rx[12] = {-1.f, 1.f, -1.f, 1.f,  0.f, 0.f, 0.f, 0.f,
                               PHI_F, PHI_F, -PHI_F, -PHI_F};
__constant__ float c_ry[12] = {PHI_F, PHI_F, -PHI_F, -PHI_F, -1.f, 1.f, -1.f, 1.f,
                               0.f, 0.f, 0.f, 0.f};
__constant__ float c_rz[12] = {0.f, 0.f, 0.f, 0.f, PHI_F, PHI_F, -PHI_F, -PHI_F,
                               -1.f, 1.f, -1.f, 1.f};
// icosahedron adjacency (deg = 5 for every vertex)
__constant__ int c_nbr[12][5] = {
    {11, 5, 1, 7, 10}, {0, 5, 7, 9, 8}, {11, 10, 3, 4, 6}, {9, 4, 2, 6, 8},
    {5, 11, 3, 9, 2},  {0, 11, 1, 9, 4}, {10, 7, 3, 2, 8}, {0, 1, 10, 6, 8},
    {7, 1, 3, 6, 9},   {1, 5, 3, 4, 8},  {0, 7, 11, 2, 6}, {0, 5, 10, 4, 2}};

__device__ __forceinline__ void vert_latlon(int v, double* olat, double* olon) {
#pragma clang fp contract(off)
  const float P = PHI_F;
  float n = sqrtf(1.0f + P * P);
  float xf = c_rx[v] / n;
  float yf = c_ry[v] / n;
  float zf = c_rz[v] / n;
  *olat = asin((double)zf);
  *olon = atan2((double)yf, (double)xf);
}

__device__ __forceinline__ double grid_lat(int i) {
#pragma clang fp contract(off)
  if (i == 720) return M_PI / 2;
  double v = (double)i * (M_PI / 720.0);
  return v - M_PI / 2;
}

__device__ __forceinline__ double grid_lon(int j) {
#pragma clang fp contract(off)
  if (j == 1439) return M_PI;
  double v = (double)j * (2.0 * M_PI / 1439.0);
  return v - M_PI;
}

__device__ __forceinline__ double d2f(double lat, double lon, double vlat,
                                      double vlon) {
#pragma clang fp contract(off)
  double dlat = lat - vlat;
  double x = (lon - vlon) + M_PI;
  const double TP = 2.0 * M_PI;
  double r = (x < 0.0) ? (x + TP) : ((x >= TP) ? (x - TP) : x);
  double dlon = r - M_PI;
  return dlat * dlat + dlon * dlon;
}

// --- k0: v2g window-argmin + vertex lat/lon (verbatim verified argmin) -----
__global__ __launch_bounds__(64) void map_kernel(char* __restrict__ ws) {
  const int t = threadIdx.x;
  if (t >= 12) return;
  int* v2g = (int*)(ws + WS_V2G);
  double* vll = (double*)(ws + WS_VLL);
  double vlat, vlon;
  vert_latlon(t, &vlat, &vlon);
  vll[t] = vlat;
  vll[12 + t] = vlon;
  int i0 = (int)floor((vlat + M_PI / 2) / (M_PI / 720.0) + 0.5);
  int j0 = (int)floor((vlon + M_PI) / (2.0 * M_PI / 1439.0) + 0.5);
  int cand[11] = {0, 1, 2, 1437, 1438, 1439, j0 - 2, j0 - 1, j0, j0 + 1, j0 + 2};
  for (int a = 6; a < 11; a++) {
    if (cand[a] < 0) cand[a] = 0;
    if (cand[a] > 1439) cand[a] = 1439;
  }
  for (int a = 1; a < 11; a++) {
    int key = cand[a];
    int p = a - 1;
    while (p >= 0 && cand[p] > key) {
      cand[p + 1] = cand[p];
      p--;
    }
    cand[p + 1] = key;
  }
  double best = 1e300;
  int bi = 0;
  for (int ii = i0 - 2; ii <= i0 + 2; ii++) {
    if (ii < 0 || ii > 720) continue;
    double lat = grid_lat(ii);
    int prev = -1;
    for (int a = 0; a < 11; a++) {
      int j = cand[a];
      if (j == prev) continue;
      prev = j;
      double dq = d2f(lat, grid_lon(j), vlat, vlon);
      if (dq < best) {  // strict < == first-occurrence (verified semantics)
        best = dq;
        bi = ii * 1440 + j;
      }
    }
  }
  v2g[t] = bi;
}

// --- k1: hn0 = feats @ W_in + b_in, one block per (batch, node) ------------
// Chain identical to verified kernel: s = b_in[d]; s += feats[c]*W_in[c*ND+d].
__global__ __launch_bounds__(256) void init_kernel(
    const float* __restrict__ x, const float* __restrict__ W_in,
    const float* __restrict__ b_in, char* __restrict__ ws) {
  __shared__ float s_f[4];
  const int blk = blockIdx.x;
  const int b = blk / 12, n = blk % 12;
  const int t = threadIdx.x;
  const int* v2g = (const int*)(ws + WS_V2G);
  float* hnA = (float*)(ws + WS_HNA);
  if (t < 4) s_f[t] = x[(size_t)(b * NC + t) * HWV + v2g[n]];
  __syncthreads();
  float s = b_in[t];
#pragma unroll
  for (int c = 0; c < 4; c++) s += s_f[c] * W_in[c * ND + t];
  hnA[(size_t)(b * 12 + n) * ND + t] = s;
}

// --- k2..k5: one GNN layer, one block per (batch, node) --------------------
// agg: same neighbor order + /5.0f. GEMM: same dd-ascending vfloat4-grouped
// fmac chain as the verified kernel. Layer 3 fuses the W_out epilogue with
// the verified serial dd-loop.
__global__ __launch_bounds__(256) void layer_kernel(
    const float* __restrict__ hsrc, float* __restrict__ hdst,
    const float* __restrict__ Wl, const float* __restrict__ bl,
    const float* __restrict__ W_out, const float* __restrict__ b_out,
    float* __restrict__ tbl, int do_out) {
  __shared__ float s_agg[ND];
  __shared__ float s_hn[ND];
  const int blk = blockIdx.x;
  const int b = blk / 12, n = blk % 12;
  const int t = threadIdx.x;

  float a = 0.f;
#pragma unroll
  for (int e = 0; e < 5; e++)
    a += hsrc[(size_t)(b * 12 + c_nbr[n][e]) * ND + t];
  s_agg[t] = a / 5.0f;
  float hold = hsrc[(size_t)(b * 12 + n) * ND + t];
  __syncthreads();

  float acc = 0.f;
  const float* W = Wl + t;
#pragma unroll 8
  for (int dd = 0; dd < ND; dd += 4) {
    vfloat4 a4 = *(const vfloat4*)&s_agg[dd];  // wave-uniform b128 broadcast
    float w0 = W[(size_t)(dd + 0) * ND];
    float w1 = W[(size_t)(dd + 1) * ND];
    float w2 = W[(size_t)(dd + 2) * ND];
    float w3 = W[(size_t)(dd + 3) * ND];
    acc += a4.x * w0; acc += a4.y * w1; acc += a4.z * w2; acc += a4.w * w3;
  }
  float u = acc + bl[t];
  float hnew = hold + ((u > 0.f) ? u : 0.f);
  hdst[(size_t)(b * 12 + n) * ND + t] = hnew;

  if (do_out) {
    s_hn[t] = hnew;
    __syncthreads();
    if (t < 4) {  // verified serial epilogue chain, c = t
      int c = t;
      float s = b_out[c];
      for (int dd = 0; dd < ND; dd++) s += s_hn[dd] * W_out[dd * 4 + c];
      tbl[b * 48 + c * 12 + n] = s;
    }
  }
}

// --- kernel 2: fused nearest-vertex mapping + scatter-write ----------------
// Identical semantics to verified kernel (strict <, row-360 twin flip);
// only change: svlat/svlon + tbl loaded from workspace instead of
// recomputed per block (same bits — produced by the same device code).
__global__ __launch_bounds__(256) void scatter_kernel(
    const char* __restrict__ ws, float* __restrict__ out) {
  __shared__ float s_tbl[NB * NC * 12];
  __shared__ double svlat[12], svlon[12];
  const int t = threadIdx.x;
  const double* vll = (const double*)(ws + WS_VLL);
  const float* tbl_g = (const float*)(ws + WS_TBL);
  if (t < 12) {
    svlat[t] = vll[t];
    svlon[t] = vll[12 + t];
  }
  for (int i = t; i < NB * NC * 12; i += 256) s_tbl[i] = tbl_g[i];
  __syncthreads();

  int q = blockIdx.x * 256 + t;
  if (q >= NQ) return;
  int h = q / 360;
  int w4 = (q - h * 360) * 4;

  int v[4];
#pragma unroll
  for (int s2 = 0; s2 < 4; s2++) {
    int kk = (w4 + s2) * 721 + h;  // reference's reshape(lon,lat).T scramble
    int i2 = kk / 1440;
    int j2 = kk - i2 * 1440;
    double lat = grid_lat(i2);
    double lon = grid_lon(j2);
    double best = 1e300;
    int bv = 0;
#pragma unroll
    for (int vv = 0; vv < 12; vv++) {
      double dd = d2f(lat, lon, svlat[vv], svlon[vv]);
      if (dd < best) {
        best = dd;
        bv = vv;
      }
    }
    // Row-360 twin flip (verified): equator crumb sign differs from XLA's
    // f32-native linspace -> flip 8<->9, 10<->11 on row 360.
    if (i2 == 360 && bv >= 8) bv ^= 1;
    v[s2] = bv;
  }

  vfloat4* out4 = (vfloat4*)out;
#pragma unroll
  for (int b = 0; b < NB; b++) {
#pragma unroll
    for (int c = 0; c < NC; c++) {
      const float* tb = &s_tbl[b * 48 + c * 12];
      vfloat4 val = {tb[v[0]], tb[v[1]], tb[v[2]], tb[v[3]]};
      __builtin_nontemporal_store(val, &out4[(size_t)(b * 4 + c) * NQ + q]);
    }
  }
}

extern "C" void kernel_launch(void* const* d_in, const int* in_sizes, int n_in,
                              void* d_out, int out_size, void* d_ws,
                              size_t ws_size, hipStream_t stream) {
  const float* x = (const float*)d_in[0];
  const float* W_in = (const float*)d_in[2];
  const float* b_in = (const float*)d_in[3];
  const float* W_layers = (const float*)d_in[4];
  const float* b_layers = (const float*)d_in[5];
  const float* W_out = (const float*)d_in[6];
  const float* b_out = (const float*)d_in[7];
  float* out = (float*)d_out;
  char* ws = (char*)d_ws;
  float* tbl = (float*)(ws + WS_TBL);
  float* hnA = (float*)(ws + WS_HNA);
  float* hnB = (float*)(ws + WS_HNB);

  map_kernel<<<1, 64, 0, stream>>>(ws);
  init_kernel<<<NB * 12, 256, 0, stream>>>(x, W_in, b_in, ws);
  const float* hs = hnA;
  float* hd = hnB;
  for (int l = 0; l < NL; l++) {
    layer_kernel<<<NB * 12, 256, 0, stream>>>(
        hs, hd, W_layers + (size_t)l * ND * ND, b_layers + (size_t)l * ND,
        W_out, b_out, tbl, (l == NL - 1) ? 1 : 0);
    const float* tmp = hd;
    hd = (float*)hs;
    hs = tmp;
  }
  int blocks = (NQ + 255) / 256;  // 1014
  scatter_kernel<<<blocks, 256, 0, stream>>>(ws, out);
}